// Round 7
// baseline (178.448 us; speedup 1.0000x reference)
//
#include <hip/hip_runtime.h>
#include <hip/hip_bf16.h>

typedef float f32x4 __attribute__((ext_vector_type(4)));
typedef float f32x16 __attribute__((ext_vector_type(16)));
typedef _Float16 half8 __attribute__((ext_vector_type(8)));
typedef __bf16 bf16x8 __attribute__((ext_vector_type(8)));
typedef __bf16 bf16x4 __attribute__((ext_vector_type(4)));
typedef unsigned short ushort_t;

constexpr int Bb = 16, Ss = 4096, Dd = 64;
constexpr int KBLK = 32, QBLK = 128;
constexpr int NT = Ss / KBLK;   // 128
constexpr float kLOG2E = 1.44269504088896340736f;
constexpr float DEFER_THR = 10.0f;   // exp2(10)=1024 max P; fp16-safe

constexpr int KP_BLOCKS = (Bb * Ss * Dd / 8) / 256;      // 2048
constexpr int VT_BLOCKS = (Bb * Dd * (Ss / 32)) / 256;   // 512

#define GLOAD_LDS16(gp, lp)                                                              \
    __builtin_amdgcn_global_load_lds(                                                    \
        (const __attribute__((address_space(1))) void*)(gp),                             \
        (__attribute__((address_space(3))) void*)(lp), 16, 0, 0)

// ------- pre-pass: K -> f16 hi/lo [b][s][d]; V -> Vt f16 [b][d][s] -------------------
__global__ __launch_bounds__(256)
void prep_f16s(const float* __restrict__ K, const float* __restrict__ V,
               _Float16* __restrict__ Khi, _Float16* __restrict__ Klo,
               _Float16* __restrict__ Vt)
{
    const int bid = blockIdx.x;
    if (bid < KP_BLOCKS) {
        const size_t idx = ((size_t)bid * 256 + threadIdx.x) * 8;
        const float4 a = *reinterpret_cast<const float4*>(K + idx);
        const float4 c = *reinterpret_cast<const float4*>(K + idx + 4);
        float xs[8] = {a.x, a.y, a.z, a.w, c.x, c.y, c.z, c.w};
        half8 h8, l8;
#pragma unroll
        for (int i = 0; i < 8; ++i) {
            const _Float16 h = (_Float16)xs[i];
            h8[i] = h;
            l8[i] = (_Float16)(xs[i] - (float)h);
        }
        *reinterpret_cast<half8*>(Khi + idx) = h8;
        *reinterpret_cast<half8*>(Klo + idx) = l8;
    } else {
        const int t = (bid - KP_BLOCKS) * 256 + threadIdx.x;
        const int d = t & 63;
        const int s32 = (t >> 6) & (Ss / 32 - 1);
        const int b = t >> 13;
        const float* vp = V + ((size_t)b * Ss + (size_t)s32 * 32) * Dd + d;
        __align__(16) _Float16 ob[32];
#pragma unroll
        for (int j = 0; j < 32; ++j) ob[j] = (_Float16)vp[(size_t)j * Dd];
        _Float16* op = Vt + ((size_t)b * Dd + d) * Ss + (size_t)s32 * 32;
#pragma unroll
        for (int j8 = 0; j8 < 4; ++j8)
            *reinterpret_cast<half8*>(op + j8 * 8) = *reinterpret_cast<half8*>(ob + j8 * 8);
    }
}

union H8 { half8 h; unsigned int u[4]; };

// ------- main v6: software-pipelined (QK(t) MFMA ∥ softmax(t-2) VALU), 8 V slots -----
// 8 waves (512 thr): wave w = (qg = w>>1) q-group (32 rows of 128), (p = w&1) k-parity.
// Grid 512 blocks = exactly 2 blocks/CU; 16 waves/CU = 4/SIMD.
// LDS 64KB: Kh 4 slots [0,16K) + Kl 4 slots [16K,32K) + Vt 8 slots [32K,64K).
__global__ __launch_bounds__(512, 4)
void attn_fwd_v6(const float* __restrict__ Q, const float* __restrict__ inv_scale,
                 const _Float16* __restrict__ Khi, const _Float16* __restrict__ Klo,
                 const _Float16* __restrict__ Vt, float* __restrict__ Out)
{
    __shared__ __align__(16) unsigned char smem[64 * 1024];

    const int tid = threadIdx.x;
    const int lane = tid & 63;
    const int w = tid >> 6;
    const int p = w & 1;
    const int qg = w >> 1;          // 0..3
    const int l31 = lane & 31;
    const int hi = lane >> 5;

    // T1 XCD swizzle: 512 blocks -> each XCD owns 64 consecutive (2 batches)
    const int bid = (blockIdx.x & 7) * 64 + (blockIdx.x >> 3);
    const int b = bid >> 5;
    const int q0 = (bid & 31) * QBLK;

    const _Float16* KhB = Khi + (size_t)b * Ss * Dd;
    const _Float16* KlB = Klo + (size_t)b * Ss * Dd;
    const _Float16* VB = Vt + (size_t)b * Dd * Ss;

    // staging: linear LDS dest, swizzle pre-applied on the GLOBAL source (rule #21).
    // waves 0-3 stage Khi+Klo, waves 4-7 stage Vt.
    const int c = tid & 255;
    const int kk = c >> 3;
    const int ksrc = kk * Dd + (((c & 7) ^ (kk & 7)) << 3);
    const int dd_ = c >> 2;
    const size_t vsrc = (size_t)dd_ * Ss + (((c & 3) ^ ((dd_ >> 1) & 3)) << 3);

#define STAGE(t)                                                                            \
    do {                                                                                    \
        if (tid < 256) {                                                                    \
            GLOAD_LDS16(KhB + (size_t)(t) * (KBLK * Dd) + ksrc,                             \
                        smem + ((t) & 3) * 4096 + c * 16);                                  \
            GLOAD_LDS16(KlB + (size_t)(t) * (KBLK * Dd) + ksrc,                             \
                        smem + 16384 + ((t) & 3) * 4096 + c * 16);                          \
        } else {                                                                            \
            GLOAD_LDS16(VB + (size_t)(t) * KBLK + vsrc,                                     \
                        smem + 32768 + ((t) & 7) * 4096 + c * 16);                          \
        }                                                                                   \
    } while (0)

    STAGE(0);
    STAGE(1);

    // LDS read byte-offsets (swizzled), constant per thread
    int koff[4], voff[4];
#pragma unroll
    for (int ks = 0; ks < 4; ++ks)
        koff[ks] = l31 * 128 + ((((ks << 1) + hi) ^ (l31 & 7)) << 4);
#pragma unroll
    for (int i = 0; i < 4; ++i) {   // i = dblk*2 + ks ; conflict-free: granule spans all 8
        const int d = (i >> 1) * 32 + l31;
        voff[i] = d * 64 + (((((i & 1) << 1) + hi) ^ ((d >> 1) & 3)) << 4);
    }

    // Q fragments f16 hi/lo, scale*log2e folded; lane: col q = l31, d = ks*16 + hi*8 ..+8
    H8 qhi[4], qlo[4];
    {
        const float s2 = (1.0f / inv_scale[0]) * kLOG2E;
        const float* qrow = Q + ((size_t)b * Ss + q0 + qg * 32 + l31) * Dd;
#pragma unroll
        for (int ks = 0; ks < 4; ++ks) {
            const int d0 = ks * 16 + hi * 8;
            const float4 a = *reinterpret_cast<const float4*>(qrow + d0);
            const float4 cc = *reinterpret_cast<const float4*>(qrow + d0 + 4);
            float xs[8] = {a.x, a.y, a.z, a.w, cc.x, cc.y, cc.z, cc.w};
#pragma unroll
            for (int i = 0; i < 8; ++i) {
                const float x = xs[i] * s2;
                const _Float16 h = (_Float16)x;
                qhi[ks].h[i] = h;
                qlo[ks].h[i] = (_Float16)(x - (float)h);
            }
        }
    }

    f32x16 Sa, Sb, O0, O1;
#pragma unroll
    for (int r = 0; r < 16; ++r) { O0[r] = 0.f; O1[r] = 0.f; Sa[r] = 0.f; Sb[r] = 0.f; }
    float m_run = -INFINITY, l_run = 0.f;

    auto xhalf = [&](unsigned int& a, unsigned int& cx) {
        const unsigned int y = hi ? a : cx;
        const unsigned int sy = __shfl_xor(y, 32);
        const unsigned int na = hi ? sy : a;
        const unsigned int nc = hi ? cx : sy;
        a = na; cx = nc;
    };

    // ---- QK: 12 MFMAs into SQK (zeroed) for tile tq ----
#define QK_STEP(IT, SQK)                                                                   \
    do {                                                                                   \
        const int _tq = 2 * (IT) + p;                                                      \
        const unsigned char* _khb = smem + (_tq & 3) * 4096;                               \
        const unsigned char* _klb = smem + 16384 + (_tq & 3) * 4096;                       \
        _Pragma("unroll") for (int r = 0; r < 16; ++r) SQK[r] = 0.f;                       \
        __builtin_amdgcn_s_setprio(1);                                                     \
        _Pragma("unroll") for (int ks = 0; ks < 4; ++ks) {                                 \
            const half8 _kh = *reinterpret_cast<const half8*>(_khb + koff[ks]);            \
            const half8 _kl = *reinterpret_cast<const half8*>(_klb + koff[ks]);            \
            SQK = __builtin_amdgcn_mfma_f32_32x32x16_f16(_kh, qhi[ks].h, SQK, 0, 0, 0);    \
            SQK = __builtin_amdgcn_mfma_f32_32x32x16_f16(_kl, qhi[ks].h, SQK, 0, 0, 0);    \
            SQK = __builtin_amdgcn_mfma_f32_32x32x16_f16(_kh, qlo[ks].h, SQK, 0, 0, 0);    \
        }                                                                                  \
        __builtin_amdgcn_s_setprio(0);                                                     \
    } while (0)

    // ---- softmax + pack + PV for tile TP held in SSM (VALU overlaps in-flight QK MFMAs)
#define SM_PV(TP, SSM)                                                                     \
    do {                                                                                   \
        float _tmax = SSM[0];                                                              \
        _Pragma("unroll") for (int r = 1; r < 16; ++r) _tmax = fmaxf(_tmax, SSM[r]);       \
        _tmax = fmaxf(_tmax, __shfl_xor(_tmax, 32));                                       \
        float _fac = 1.0f;                                                                 \
        if (__any(_tmax > m_run + DEFER_THR)) {                                            \
            const float _mn = fmaxf(m_run, _tmax);                                         \
            _fac = __builtin_amdgcn_exp2f(m_run - _mn);                                    \
            m_run = _mn;                                                                   \
            _Pragma("unroll") for (int r = 0; r < 16; ++r) { O0[r] *= _fac; O1[r] *= _fac; } \
        }                                                                                  \
        float _tsum = 0.f;                                                                 \
        _Pragma("unroll") for (int r = 0; r < 16; ++r) {                                   \
            SSM[r] = __builtin_amdgcn_exp2f(SSM[r] - m_run);                               \
            _tsum += SSM[r];                                                               \
        }                                                                                  \
        _tsum += __shfl_xor(_tsum, 32);                                                    \
        l_run = l_run * _fac + _tsum;                                                      \
        unsigned int _wd[8];                                                               \
        _Pragma("unroll") for (int j = 0; j < 8; ++j) {                                    \
            const auto _h2 = __builtin_amdgcn_cvt_pkrtz(SSM[2 * j], SSM[2 * j + 1]);       \
            _wd[j] = __builtin_bit_cast(unsigned int, _h2);                                \
        }                                                                                  \
        xhalf(_wd[0], _wd[2]); xhalf(_wd[1], _wd[3]);                                      \
        xhalf(_wd[4], _wd[6]); xhalf(_wd[5], _wd[7]);                                      \
        H8 _pf0, _pf1;                                                                     \
        _pf0.u[0] = _wd[0]; _pf0.u[1] = _wd[1]; _pf0.u[2] = _wd[2]; _pf0.u[3] = _wd[3];    \
        _pf1.u[0] = _wd[4]; _pf1.u[1] = _wd[5]; _pf1.u[2] = _wd[6]; _pf1.u[3] = _wd[7];    \
        const unsigned char* _vb = smem + 32768 + ((TP) & 7) * 4096;                       \
        __builtin_amdgcn_s_setprio(1);                                                     \
        O0 = __builtin_amdgcn_mfma_f32_32x32x16_f16(                                       \
            *reinterpret_cast<const half8*>(_vb + voff[0]), _pf0.h, O0, 0, 0, 0);          \
        O0 = __builtin_amdgcn_mfma_f32_32x32x16_f16(                                       \
            *reinterpret_cast<const half8*>(_vb + voff[1]), _pf1.h, O0, 0, 0, 0);          \
        O1 = __builtin_amdgcn_mfma_f32_32x32x16_f16(                                       \
            *reinterpret_cast<const half8*>(_vb + voff[2]), _pf0.h, O1, 0, 0, 0);          \
        O1 = __builtin_amdgcn_mfma_f32_32x32x16_f16(                                       \
            *reinterpret_cast<const half8*>(_vb + voff[3]), _pf1.h, O1, 0, 0, 0);          \
        __builtin_amdgcn_s_setprio(0);                                                     \
    } while (0)

    __syncthreads();   // tiles 0,1 resident

    // peeled first iteration (it=0): QK only
    STAGE(2); STAGE(3);
    QK_STEP(0, Sa);
    __syncthreads();

    // main pipeline: it = 1..62 (two per trip, explicit Sa/Sb roles — rule #20)
    for (int ih = 0; ih < 31; ++ih) {
        const int itA = 2 * ih + 1;
        STAGE(2 * itA + 2); STAGE(2 * itA + 3);
        QK_STEP(itA, Sb);
        SM_PV(2 * itA - 2 + p, Sa);
        __syncthreads();

        const int itB = 2 * ih + 2;
        STAGE(2 * itB + 2); STAGE(2 * itB + 3);
        QK_STEP(itB, Sa);
        SM_PV(2 * itB - 2 + p, Sb);
        __syncthreads();
    }

    // it = 63: QK -> Sb, softmax/PV on Sa (tile 124+p)
    QK_STEP(63, Sb);
    SM_PV(124 + p, Sa);
    __syncthreads();

    // epilogue: softmax/PV on Sb (tile 126+p)
    SM_PV(126 + p, Sb);

    // ---- merge k-parity pairs (wave p=1 -> LDS; wave p=0 combines, stores) ----
    float* mO = (float*)smem;                 // [qg][dblk][rr][256] : 32KB (K region, safe)
    float* ml = (float*)(smem + 32768);       // 1KB (V slot 0 region, post-PV safe)

    if (p == 1) {
#pragma unroll
        for (int dblk = 0; dblk < 2; ++dblk)
#pragma unroll
            for (int rr = 0; rr < 4; ++rr) {
                f32x4 v;
                if (dblk == 0) {
                    v[0] = O0[rr * 4 + 0]; v[1] = O0[rr * 4 + 1];
                    v[2] = O0[rr * 4 + 2]; v[3] = O0[rr * 4 + 3];
                } else {
                    v[0] = O1[rr * 4 + 0]; v[1] = O1[rr * 4 + 1];
                    v[2] = O1[rr * 4 + 2]; v[3] = O1[rr * 4 + 3];
                }
                *reinterpret_cast<f32x4*>(mO + (((qg * 2 + dblk) * 4 + rr) << 8) + lane * 4) = v;
            }
        if (hi == 0) {
            ml[qg * 64 + l31] = m_run;
            ml[qg * 64 + 32 + l31] = l_run;
        }
    }
    __syncthreads();
    if (p == 0) {
        const float m1 = ml[qg * 64 + l31];
        const float l1 = ml[qg * 64 + 32 + l31];
        const float mm = fmaxf(m_run, m1);
        float f0 = __builtin_amdgcn_exp2f(m_run - mm);
        float f1 = __builtin_amdgcn_exp2f(m1 - mm);
        const float inv = 1.0f / (l_run * f0 + l1 * f1);
        f0 *= inv; f1 *= inv;
        float* orow = Out + ((size_t)b * Ss + q0 + qg * 32 + l31) * Dd;
#pragma unroll
        for (int dblk = 0; dblk < 2; ++dblk)
#pragma unroll
            for (int rr = 0; rr < 4; ++rr) {
                const f32x4 ov = *reinterpret_cast<const f32x4*>(
                    mO + (((qg * 2 + dblk) * 4 + rr) << 8) + lane * 4);
                f32x4 res;
#pragma unroll
                for (int j = 0; j < 4; ++j) {
                    const float mine = (dblk == 0) ? O0[rr * 4 + j] : O1[rr * 4 + j];
                    res[j] = mine * f0 + ov[j] * f1;
                }
                *reinterpret_cast<f32x4*>(orow + dblk * 32 + rr * 8 + hi * 4) = res;
            }
    }
#undef STAGE
#undef QK_STEP
#undef SM_PV
}

// ---------------- fallback (validated round-1 kernel) if workspace too small ---------
__global__ __launch_bounds__(256)
void attn_fwd_fallback(const float* __restrict__ Q, const float* __restrict__ K,
                       const float* __restrict__ V, const float* __restrict__ inv_scale,
                       float* __restrict__ Out)
{
    __shared__ __align__(16) ushort_t sKhi[KBLK * Dd];
    __shared__ __align__(16) ushort_t sKlo[KBLK * Dd];
    __shared__ __align__(16) ushort_t sVt[Dd * KBLK];
    __shared__ __align__(16) ushort_t sP[4][16 * KBLK];

    const int tid = threadIdx.x;
    const int lane = tid & 63;
    const int w = tid >> 6;
    const int q15 = lane & 15;
    const int g = lane >> 4;
    const int b = blockIdx.x >> 6;
    const int q0 = (blockIdx.x & 63) * 64;
    const float scale = 1.0f / inv_scale[0];

    const float* qptr = Q + (((size_t)b * Ss) + q0 + w * 16 + q15) * Dd;
    bf16x8 qhi[2], qlo[2];
#pragma unroll
    for (int ds = 0; ds < 2; ++ds) {
        const float4 f0 = *reinterpret_cast<const float4*>(qptr + ds * 32 + g * 8);
        const float4 f1 = *reinterpret_cast<const float4*>(qptr + ds * 32 + g * 8 + 4);
        float xs[8] = {f0.x, f0.y, f0.z, f0.w, f1.x, f1.y, f1.z, f1.w};
#pragma unroll
        for (int i = 0; i < 8; ++i) {
            __bf16 h = (__bf16)xs[i];
            qhi[ds][i] = h;
            qlo[ds][i] = (__bf16)(xs[i] - (float)h);
        }
    }
    const int krs = tid >> 3;
    const int kc8 = (tid & 7) * 8;
    const int kidx = krs * Dd + (kc8 ^ ((krs & 7) << 3));
    const float* kbase = K + ((size_t)b * Ss) * Dd;
    const int vd = tid & 63;
    const int vk8 = (tid >> 6) * 8;
    const int vidx = vd * KBLK + (vk8 ^ ((vd & 3) << 3));
    const float* vbase = V + ((size_t)b * Ss) * Dd;

    f32x4 Oacc[4];
#pragma unroll
    for (int dt = 0; dt < 4; ++dt)
#pragma unroll
        for (int r = 0; r < 4; ++r) Oacc[dt][r] = 0.f;
    float m_run = -INFINITY, l_run = 0.f;

    for (int k0 = 0; k0 < Ss; k0 += KBLK) {
        {
            const float* p0 = kbase + (size_t)(k0 + krs) * Dd + kc8;
            const float4 a = *reinterpret_cast<const float4*>(p0);
            const float4 c = *reinterpret_cast<const float4*>(p0 + 4);
            float xs[8] = {a.x, a.y, a.z, a.w, c.x, c.y, c.z, c.w};
            bf16x8 h8, l8;
#pragma unroll
            for (int i = 0; i < 8; ++i) {
                __bf16 h = (__bf16)xs[i];
                h8[i] = h;
                l8[i] = (__bf16)(xs[i] - (float)h);
            }
            *reinterpret_cast<bf16x8*>(&sKhi[kidx]) = h8;
            *reinterpret_cast<bf16x8*>(&sKlo[kidx]) = l8;
        }
        {
            bf16x8 v8;
#pragma unroll
            for (int j = 0; j < 8; ++j) v8[j] = (__bf16)vbase[(size_t)(k0 + vk8 + j) * Dd + vd];
            *reinterpret_cast<bf16x8*>(&sVt[vidx]) = v8;
        }
        __syncthreads();

        float z[2][4];
#pragma unroll
        for (int t = 0; t < 2; ++t) {
            const int krow = t * 16 + q15;
            f32x4 acc;
            acc[0] = acc[1] = acc[2] = acc[3] = 0.f;
#pragma unroll
            for (int ds = 0; ds < 2; ++ds) {
                const int ci = (ds * 32 + g * 8) ^ ((krow & 7) << 3);
                const bf16x8 kh = *reinterpret_cast<const bf16x8*>(&sKhi[krow * Dd + ci]);
                const bf16x8 kl = *reinterpret_cast<const bf16x8*>(&sKlo[krow * Dd + ci]);
                acc = __builtin_amdgcn_mfma_f32_16x16x32_bf16(kh, qhi[ds], acc, 0, 0, 0);
                acc = __builtin_amdgcn_mfma_f32_16x16x32_bf16(kl, qhi[ds], acc, 0, 0, 0);
                acc = __builtin_amdgcn_mfma_f32_16x16x32_bf16(kh, qlo[ds], acc, 0, 0, 0);
            }
#pragma unroll
            for (int r = 0; r < 4; ++r) z[t][r] = acc[r] * scale;
        }

        float tmax = z[0][0];
#pragma unroll
        for (int t = 0; t < 2; ++t)
#pragma unroll
            for (int r = 0; r < 4; ++r) tmax = fmaxf(tmax, z[t][r]);
        tmax = fmaxf(tmax, __shfl_xor(tmax, 16));
        tmax = fmaxf(tmax, __shfl_xor(tmax, 32));
        const float m_new = fmaxf(m_run, tmax);

        float pz[2][4];
        float tsum = 0.f;
#pragma unroll
        for (int t = 0; t < 2; ++t)
#pragma unroll
            for (int r = 0; r < 4; ++r) {
                const float e = __builtin_amdgcn_exp2f((z[t][r] - m_new) * kLOG2E);
                pz[t][r] = e;
                tsum += e;
            }
        tsum += __shfl_xor(tsum, 16);
        tsum += __shfl_xor(tsum, 32);
        const float fac = __builtin_amdgcn_exp2f((m_run - m_new) * kLOG2E);
        l_run = l_run * fac + tsum;
        m_run = m_new;

#pragma unroll
        for (int t = 0; t < 2; ++t) {
            bf16x4 pb;
#pragma unroll
            for (int r = 0; r < 4; ++r) pb[r] = (__bf16)pz[t][r];
            const int pidx = q15 * KBLK + ((t * 16 + g * 4) ^ ((q15 & 3) << 3));
            *reinterpret_cast<bf16x4*>(&sP[w][pidx]) = pb;
        }
        {
            const float fr0 = __shfl(fac, g * 4 + 0);
            const float fr1 = __shfl(fac, g * 4 + 1);
            const float fr2 = __shfl(fac, g * 4 + 2);
            const float fr3 = __shfl(fac, g * 4 + 3);
#pragma unroll
            for (int dt = 0; dt < 4; ++dt) {
                Oacc[dt][0] *= fr0; Oacc[dt][1] *= fr1;
                Oacc[dt][2] *= fr2; Oacc[dt][3] *= fr3;
            }
        }
        const int paidx = q15 * KBLK + ((g * 8) ^ ((q15 & 3) << 3));
        const bf16x8 pa = *reinterpret_cast<const bf16x8*>(&sP[w][paidx]);
#pragma unroll
        for (int dt = 0; dt < 4; ++dt) {
            const int dd = dt * 16 + q15;
            const bf16x8 vf =
                *reinterpret_cast<const bf16x8*>(&sVt[dd * KBLK + ((g * 8) ^ ((dd & 3) << 3))]);
            Oacc[dt] = __builtin_amdgcn_mfma_f32_16x16x32_bf16(pa, vf, Oacc[dt], 0, 0, 0);
        }
        __syncthreads();
    }

    const float invl = 1.0f / l_run;
    float il[4];
#pragma unroll
    for (int r = 0; r < 4; ++r) il[r] = __shfl(invl, g * 4 + r);
    float* obase = Out + (((size_t)b * Ss) + q0 + w * 16) * Dd;
#pragma unroll
    for (int dt = 0; dt < 4; ++dt)
#pragma unroll
        for (int r = 0; r < 4; ++r)
            obase[(size_t)(g * 4 + r) * Dd + dt * 16 + q15] = Oacc[dt][r] * il[r];
}

extern "C" void kernel_launch(void* const* d_in, const int* in_sizes, int n_in,
                              void* d_out, int out_size, void* d_ws, size_t ws_size,
                              hipStream_t stream)
{
    const float* q = (const float*)d_in[0];
    const float* k = (const float*)d_in[1];
    const float* v = (const float*)d_in[2];
    const float* inv_scale = (const float*)d_in[3];
    float* out = (float*)d_out;
    (void)in_sizes; (void)n_in; (void)out_size;

    const size_t NKV = (size_t)Bb * Ss * Dd;                 // elements per K/V tensor
    const size_t need = NKV * 3 * sizeof(_Float16);          // Khi + Klo + Vt

    if (ws_size >= need) {
        _Float16* Khi = (_Float16*)d_ws;
        _Float16* Klo = Khi + NKV;
        _Float16* Vt = Klo + NKV;
        hipLaunchKernelGGL(prep_f16s, dim3(KP_BLOCKS + VT_BLOCKS), dim3(256), 0, stream,
                           k, v, Khi, Klo, Vt);
        hipLaunchKernelGGL(attn_fwd_v6, dim3(Bb * (Ss / QBLK)), dim3(512), 0, stream,
                           q, inv_scale, Khi, Klo, Vt, out);
    } else {
        hipLaunchKernelGGL(attn_fwd_fallback, dim3(Bb * 64), dim3(256), 0, stream,
                           q, k, v, inv_scale, out);
    }
}

// Round 10
// 175.541 us; speedup vs baseline: 1.0166x; 1.0166x over previous
//
#include <hip/hip_runtime.h>
#include <hip/hip_bf16.h>

typedef float f32x4 __attribute__((ext_vector_type(4)));
typedef float f32x16 __attribute__((ext_vector_type(16)));
typedef _Float16 half8 __attribute__((ext_vector_type(8)));
typedef __bf16 bf16x8 __attribute__((ext_vector_type(8)));
typedef __bf16 bf16x4 __attribute__((ext_vector_type(4)));
typedef unsigned short ushort_t;

constexpr int Bb = 16, Ss = 4096, Dd = 64;
constexpr int KBLK = 32, QBLK = 128;
constexpr int NT = Ss / KBLK;   // 128
constexpr float kLOG2E = 1.44269504088896340736f;
constexpr float DEFER_THR = 10.0f;   // exp2(10)=1024 max P; fp16-safe

constexpr int KP_BLOCKS = (Bb * Ss * Dd / 8) / 256;      // 2048
constexpr int VT_BLOCKS = (Bb * Dd * (Ss / 32)) / 256;   // 512

#define GLOAD_LDS16(gp, lp)                                                              \
    __builtin_amdgcn_global_load_lds(                                                    \
        (const __attribute__((address_space(1))) void*)(gp),                             \
        (__attribute__((address_space(3))) void*)(lp), 16, 0, 0)

// ------- pre-pass: K -> f16 hi/lo [b][s][d]; V -> Vt f16 [b][d][s] (round-6 verified) -
__global__ __launch_bounds__(256)
void prep_f16s(const float* __restrict__ K, const float* __restrict__ V,
               _Float16* __restrict__ Khi, _Float16* __restrict__ Klo,
               _Float16* __restrict__ Vt)
{
    const int bid = blockIdx.x;
    if (bid < KP_BLOCKS) {
        const size_t idx = ((size_t)bid * 256 + threadIdx.x) * 8;
        const float4 a = *reinterpret_cast<const float4*>(K + idx);
        const float4 c = *reinterpret_cast<const float4*>(K + idx + 4);
        float xs[8] = {a.x, a.y, a.z, a.w, c.x, c.y, c.z, c.w};
        half8 h8, l8;
#pragma unroll
        for (int i = 0; i < 8; ++i) {
            const _Float16 h = (_Float16)xs[i];
            h8[i] = h;
            l8[i] = (_Float16)(xs[i] - (float)h);
        }
        *reinterpret_cast<half8*>(Khi + idx) = h8;
        *reinterpret_cast<half8*>(Klo + idx) = l8;
    } else {
        const int t = (bid - KP_BLOCKS) * 256 + threadIdx.x;
        const int d = t & 63;
        const int s32 = (t >> 6) & (Ss / 32 - 1);
        const int b = t >> 13;
        const float* vp = V + ((size_t)b * Ss + (size_t)s32 * 32) * Dd + d;
        __align__(16) _Float16 ob[32];
#pragma unroll
        for (int j = 0; j < 32; ++j) ob[j] = (_Float16)vp[(size_t)j * Dd];
        _Float16* op = Vt + ((size_t)b * Dd + d) * Ss + (size_t)s32 * 32;
#pragma unroll
        for (int j8 = 0; j8 < 4; ++j8)
            *reinterpret_cast<half8*>(op + j8 * 8) = *reinterpret_cast<half8*>(ob + j8 * 8);
    }
}

union H8 { half8 h; unsigned int u[4]; };

// ------- main v10: 3-pass split-fp16 QK, 64 q-rows/wave (2 S chains), O^T PV ---------
// Cross-half ops use the v5-VERIFIED __shfl_xor forms (round-9 asm permlane was buggy).
// 4 waves (256 thr): wave w = (qg = w>>1) q-group (64 rows of 128), (p = w&1) k-parity.
// Grid 512 blocks = 2 blocks/CU; 8 waves/CU = 2/SIMD (each wave has 2x ILP).
// LDS 48KB: Khi 4 slots [0,16K) + Klo [16K,32K) + Vt [32K,48K); merge overlays.
__global__ __launch_bounds__(256, 2)
void attn_fwd_v10(const float* __restrict__ Q, const float* __restrict__ inv_scale,
                  const _Float16* __restrict__ Khi, const _Float16* __restrict__ Klo,
                  const _Float16* __restrict__ Vt, float* __restrict__ Out)
{
    __shared__ __align__(16) unsigned char smem[48 * 1024];

    const int tid = threadIdx.x;
    const int lane = tid & 63;
    const int w = tid >> 6;
    const int p = w & 1;
    const int qg = w >> 1;          // 0..1, owns q-rows [qg*64, qg*64+64)
    const int l31 = lane & 31;
    const int hi = lane >> 5;

    // T1 XCD swizzle: 512 blocks -> each XCD owns 64 consecutive (2 batches)
    const int bid = (blockIdx.x & 7) * 64 + (blockIdx.x >> 3);
    const int b = bid >> 5;
    const int q0 = (bid & 31) * QBLK;

    const _Float16* KhB = Khi + (size_t)b * Ss * Dd;
    const _Float16* KlB = Klo + (size_t)b * Ss * Dd;
    const _Float16* VB = Vt + (size_t)b * Dd * Ss;

    // staging: linear LDS dest, swizzle pre-applied on GLOBAL source (rule #21).
    const int kk = tid >> 3;
    const int ksrc = kk * Dd + (((tid & 7) ^ (kk & 7)) << 3);
    const int dd_ = tid >> 2;
    const size_t vsrc = (size_t)dd_ * Ss + (((tid & 3) ^ ((dd_ >> 1) & 3)) << 3);

#define STAGE(t)                                                                            \
    do {                                                                                    \
        GLOAD_LDS16(KhB + (size_t)(t) * (KBLK * Dd) + ksrc,                                 \
                    smem + ((t) & 3) * 4096 + tid * 16);                                    \
        GLOAD_LDS16(KlB + (size_t)(t) * (KBLK * Dd) + ksrc,                                 \
                    smem + 16384 + ((t) & 3) * 4096 + tid * 16);                            \
        GLOAD_LDS16(VB + (size_t)(t) * KBLK + vsrc,                                         \
                    smem + 32768 + ((t) & 3) * 4096 + tid * 16);                            \
    } while (0)

    STAGE(0);
    STAGE(1);

    // LDS read byte-offsets (swizzled), constant per thread
    int koff[4], voff[4];
#pragma unroll
    for (int ks = 0; ks < 4; ++ks)
        koff[ks] = l31 * 128 + ((((ks << 1) + hi) ^ (l31 & 7)) << 4);
#pragma unroll
    for (int i = 0; i < 4; ++i) {   // i = dblk*2 + ks ; conflict-free V swizzle (r7-verified)
        const int d = (i >> 1) * 32 + l31;
        voff[i] = d * 64 + (((((i & 1) << 1) + hi) ^ ((d >> 1) & 3)) << 4);
    }

    // Q fragments f16 hi/lo for 2 q-sub-blocks; lane: col q = l31, d = ks*16 + hi*8 ..+8
    H8 qhi[2][4], qlo[2][4];
    {
        const float s2 = (1.0f / inv_scale[0]) * kLOG2E;
#pragma unroll
        for (int qs = 0; qs < 2; ++qs) {
            const float* qrow =
                Q + ((size_t)b * Ss + q0 + qg * 64 + qs * 32 + l31) * Dd;
#pragma unroll
            for (int ks = 0; ks < 4; ++ks) {
                const int d0 = ks * 16 + hi * 8;
                const float4 a = *reinterpret_cast<const float4*>(qrow + d0);
                const float4 cc = *reinterpret_cast<const float4*>(qrow + d0 + 4);
                float xs[8] = {a.x, a.y, a.z, a.w, cc.x, cc.y, cc.z, cc.w};
#pragma unroll
                for (int i = 0; i < 8; ++i) {
                    const float x = xs[i] * s2;
                    const _Float16 h = (_Float16)x;
                    qhi[qs][ks].h[i] = h;
                    qlo[qs][ks].h[i] = (_Float16)(x - (float)h);
                }
            }
        }
    }

    f32x16 O0, O1, O2, O3;   // O0/O1: qs=0 dblk0/1 ; O2/O3: qs=1
#pragma unroll
    for (int r = 0; r < 16; ++r) { O0[r] = 0.f; O1[r] = 0.f; O2[r] = 0.f; O3[r] = 0.f; }
    float m0 = -INFINITY, l0 = 0.f, m1 = -INFINITY, l1 = 0.f;

    // v5-verified cross-half exchange (4 ops, shfl-based)
    auto xhalf = [&](unsigned int& a, unsigned int& cx) {
        const unsigned int y = hi ? a : cx;
        const unsigned int sy = __shfl_xor(y, 32);
        const unsigned int na = hi ? sy : a;
        const unsigned int nc = hi ? cx : sy;
        a = na; cx = nc;
    };

    __syncthreads();   // tiles 0,1 resident (barrier drains vmcnt)

    for (int it = 0; it < NT / 2; ++it) {
        const int t = 2 * it + p;
        const unsigned char* khbase = smem + (t & 3) * 4096;
        const unsigned char* klbase = smem + 16384 + (t & 3) * 4096;
        const unsigned char* vbase = smem + 32768 + (t & 3) * 4096;

        if (it < NT / 2 - 1) { STAGE(2 * it + 2); STAGE(2 * it + 3); }

        // ---- S^T = K·Q^T for BOTH q-sub-blocks: 8 K reads -> 24 MFMAs ----
        f32x16 S0, S1;
#pragma unroll
        for (int r = 0; r < 16; ++r) { S0[r] = 0.f; S1[r] = 0.f; }
        __builtin_amdgcn_s_setprio(1);
#pragma unroll
        for (int ks = 0; ks < 4; ++ks) {
            const half8 kh = *reinterpret_cast<const half8*>(khbase + koff[ks]);
            const half8 kl = *reinterpret_cast<const half8*>(klbase + koff[ks]);
            S0 = __builtin_amdgcn_mfma_f32_32x32x16_f16(kh, qhi[0][ks].h, S0, 0, 0, 0);
            S1 = __builtin_amdgcn_mfma_f32_32x32x16_f16(kh, qhi[1][ks].h, S1, 0, 0, 0);
            S0 = __builtin_amdgcn_mfma_f32_32x32x16_f16(kl, qhi[0][ks].h, S0, 0, 0, 0);
            S1 = __builtin_amdgcn_mfma_f32_32x32x16_f16(kl, qhi[1][ks].h, S1, 0, 0, 0);
            S0 = __builtin_amdgcn_mfma_f32_32x32x16_f16(kh, qlo[0][ks].h, S0, 0, 0, 0);
            S1 = __builtin_amdgcn_mfma_f32_32x32x16_f16(kh, qlo[1][ks].h, S1, 0, 0, 0);
        }
        __builtin_amdgcn_s_setprio(0);

        // ---- online softmax (log2 domain), defer-max, both chains ----
        float t0 = S0[0], t1 = S1[0];
#pragma unroll
        for (int r = 1; r < 16; ++r) { t0 = fmaxf(t0, S0[r]); t1 = fmaxf(t1, S1[r]); }
        t0 = fmaxf(t0, __shfl_xor(t0, 32));
        t1 = fmaxf(t1, __shfl_xor(t1, 32));

        float fac0 = 1.0f, fac1 = 1.0f;
        if (__any(fmaxf(t0 - m0, t1 - m1) > DEFER_THR)) {
            const float mn0 = fmaxf(m0, t0);
            fac0 = __builtin_amdgcn_exp2f(m0 - mn0);
            m0 = mn0;
            const float mn1 = fmaxf(m1, t1);
            fac1 = __builtin_amdgcn_exp2f(m1 - mn1);
            m1 = mn1;
#pragma unroll
            for (int r = 0; r < 16; ++r) {
                O0[r] *= fac0; O1[r] *= fac0;
                O2[r] *= fac1; O3[r] *= fac1;
            }
        }

        float ts0 = 0.f, ts1 = 0.f;
#pragma unroll
        for (int r = 0; r < 16; ++r) {
            S0[r] = __builtin_amdgcn_exp2f(S0[r] - m0);
            ts0 += S0[r];
            S1[r] = __builtin_amdgcn_exp2f(S1[r] - m1);
            ts1 += S1[r];
        }
        ts0 += __shfl_xor(ts0, 32);
        ts1 += __shfl_xor(ts1, 32);
        l0 = l0 * fac0 + ts0;
        l1 = l1 * fac1 + ts1;

        // ---- pack P to f16, cross-half exchange (v5-verified xhalf) ----
        unsigned int wa[8], wb[8];
#pragma unroll
        for (int j = 0; j < 8; ++j) {
            const auto ha = __builtin_amdgcn_cvt_pkrtz(S0[2 * j], S0[2 * j + 1]);
            wa[j] = __builtin_bit_cast(unsigned int, ha);
            const auto hb = __builtin_amdgcn_cvt_pkrtz(S1[2 * j], S1[2 * j + 1]);
            wb[j] = __builtin_bit_cast(unsigned int, hb);
        }
        xhalf(wa[0], wa[2]); xhalf(wa[1], wa[3]);
        xhalf(wa[4], wa[6]); xhalf(wa[5], wa[7]);
        xhalf(wb[0], wb[2]); xhalf(wb[1], wb[3]);
        xhalf(wb[4], wb[6]); xhalf(wb[5], wb[7]);

        H8 pa0, pa1, pb0, pb1;
        pa0.u[0] = wa[0]; pa0.u[1] = wa[1]; pa0.u[2] = wa[2]; pa0.u[3] = wa[3];
        pa1.u[0] = wa[4]; pa1.u[1] = wa[5]; pa1.u[2] = wa[6]; pa1.u[3] = wa[7];
        pb0.u[0] = wb[0]; pb0.u[1] = wb[1]; pb0.u[2] = wb[2]; pb0.u[3] = wb[3];
        pb1.u[0] = wb[4]; pb1.u[1] = wb[5]; pb1.u[2] = wb[6]; pb1.u[3] = wb[7];

        // ---- O^T += V^T · P : 4 V reads -> 8 MFMAs (V frags shared across qs) ----
        const half8 vf0 = *reinterpret_cast<const half8*>(vbase + voff[0]);
        const half8 vf1 = *reinterpret_cast<const half8*>(vbase + voff[1]);
        const half8 vf2 = *reinterpret_cast<const half8*>(vbase + voff[2]);
        const half8 vf3 = *reinterpret_cast<const half8*>(vbase + voff[3]);
        __builtin_amdgcn_s_setprio(1);
        O0 = __builtin_amdgcn_mfma_f32_32x32x16_f16(vf0, pa0.h, O0, 0, 0, 0);
        O2 = __builtin_amdgcn_mfma_f32_32x32x16_f16(vf0, pb0.h, O2, 0, 0, 0);
        O0 = __builtin_amdgcn_mfma_f32_32x32x16_f16(vf1, pa1.h, O0, 0, 0, 0);
        O2 = __builtin_amdgcn_mfma_f32_32x32x16_f16(vf1, pb1.h, O2, 0, 0, 0);
        O1 = __builtin_amdgcn_mfma_f32_32x32x16_f16(vf2, pa0.h, O1, 0, 0, 0);
        O3 = __builtin_amdgcn_mfma_f32_32x32x16_f16(vf2, pb0.h, O3, 0, 0, 0);
        O1 = __builtin_amdgcn_mfma_f32_32x32x16_f16(vf3, pa1.h, O1, 0, 0, 0);
        O3 = __builtin_amdgcn_mfma_f32_32x32x16_f16(vf3, pb1.h, O3, 0, 0, 0);
        __builtin_amdgcn_s_setprio(0);

        __syncthreads();   // staged tiles ready; slots free for reuse
    }

    // ---- merge k-parity pairs, 2 rounds (qs=0 then qs=1) ----
    float* mO = (float*)smem;                 // [qg*2+dblk][rr][256] : 16KB overlay
    float* ml = (float*)(smem + 16384);       // [qg][{m,l}][32]

#define MERGE_ROUND(OA, OB, MV, LV, QS)                                                     \
    do {                                                                                    \
        if (p == 1) {                                                                       \
            _Pragma("unroll") for (int rr = 0; rr < 4; ++rr) {                              \
                f32x4 va, vb;                                                               \
                _Pragma("unroll") for (int j = 0; j < 4; ++j) {                             \
                    va[j] = OA[rr * 4 + j];                                                 \
                    vb[j] = OB[rr * 4 + j];                                                 \
                }                                                                           \
                *reinterpret_cast<f32x4*>(mO + (((qg * 2 + 0) * 4 + rr) << 8) + lane * 4) = \
                    va;                                                                     \
                *reinterpret_cast<f32x4*>(mO + (((qg * 2 + 1) * 4 + rr) << 8) + lane * 4) = \
                    vb;                                                                     \
            }                                                                               \
            if (hi == 0) {                                                                  \
                ml[qg * 64 + l31] = MV;                                                     \
                ml[qg * 64 + 32 + l31] = LV;                                                \
            }                                                                               \
        }                                                                                   \
        __syncthreads();                                                                    \
        if (p == 0) {                                                                       \
            const float m_o = ml[qg * 64 + l31];                                            \
            const float l_o = ml[qg * 64 + 32 + l31];                                       \
            const float mm = fmaxf(MV, m_o);                                                \
            float f0 = __builtin_amdgcn_exp2f(MV - mm);                                     \
            float f1 = __builtin_amdgcn_exp2f(m_o - mm);                                    \
            const float inv = 1.0f / (LV * f0 + l_o * f1);                                  \
            f0 *= inv; f1 *= inv;                                                           \
            float* orow = Out + ((size_t)b * Ss + q0 + qg * 64 + (QS) * 32 + l31) * Dd;     \
            _Pragma("unroll") for (int dblk = 0; dblk < 2; ++dblk) {                        \
                _Pragma("unroll") for (int rr = 0; rr < 4; ++rr) {                          \
                    const f32x4 ov = *reinterpret_cast<const f32x4*>(                       \
                        mO + (((qg * 2 + dblk) * 4 + rr) << 8) + lane * 4);                 \
                    f32x4 res;                                                              \
                    _Pragma("unroll") for (int j = 0; j < 4; ++j) {                         \
                        const float mine =                                                  \
                            (dblk == 0) ? OA[rr * 4 + j] : OB[rr * 4 + j];                  \
                        res[j] = mine * f0 + ov[j] * f1;                                    \
                    }                                                                       \
                    *reinterpret_cast<f32x4*>(orow + dblk * 32 + rr * 8 + hi * 4) = res;    \
                }                                                                           \
            }                                                                               \
        }                                                                                   \
        __syncthreads();                                                                    \
    } while (0)

    MERGE_ROUND(O0, O1, m0, l0, 0);
    MERGE_ROUND(O2, O3, m1, l1, 1);
#undef MERGE_ROUND
#undef STAGE
}

// ---------------- fallback (validated round-1 kernel) if workspace too small ---------
__global__ __launch_bounds__(256)
void attn_fwd_fallback(const float* __restrict__ Q, const float* __restrict__ K,
                       const float* __restrict__ V, const float* __restrict__ inv_scale,
                       float* __restrict__ Out)
{
    __shared__ __align__(16) ushort_t sKhi[KBLK * Dd];
    __shared__ __align__(16) ushort_t sKlo[KBLK * Dd];
    __shared__ __align__(16) ushort_t sVt[Dd * KBLK];
    __shared__ __align__(16) ushort_t sP[4][16 * KBLK];

    const int tid = threadIdx.x;
    const int lane = tid & 63;
    const int w = tid >> 6;
    const int q15 = lane & 15;
    const int g = lane >> 4;
    const int b = blockIdx.x >> 6;
    const int q0 = (blockIdx.x & 63) * 64;
    const float scale = 1.0f / inv_scale[0];

    const float* qptr = Q + (((size_t)b * Ss) + q0 + w * 16 + q15) * Dd;
    bf16x8 qhi[2], qlo[2];
#pragma unroll
    for (int ds = 0; ds < 2; ++ds) {
        const float4 f0 = *reinterpret_cast<const float4*>(qptr + ds * 32 + g * 8);
        const float4 f1 = *reinterpret_cast<const float4*>(qptr + ds * 32 + g * 8 + 4);
        float xs[8] = {f0.x, f0.y, f0.z, f0.w, f1.x, f1.y, f1.z, f1.w};
#pragma unroll
        for (int i = 0; i < 8; ++i) {
            __bf16 h = (__bf16)xs[i];
            qhi[ds][i] = h;
            qlo[ds][i] = (__bf16)(xs[i] - (float)h);
        }
    }
    const int krs = tid >> 3;
    const int kc8 = (tid & 7) * 8;
    const int kidx = krs * Dd + (kc8 ^ ((krs & 7) << 3));
    const float* kbase = K + ((size_t)b * Ss) * Dd;
    const int vd = tid & 63;
    const int vk8 = (tid >> 6) * 8;
    const int vidx = vd * KBLK + (vk8 ^ ((vd & 3) << 3));
    const float* vbase = V + ((size_t)b * Ss) * Dd;

    f32x4 Oacc[4];
#pragma unroll
    for (int dt = 0; dt < 4; ++dt)
#pragma unroll
        for (int r = 0; r < 4; ++r) Oacc[dt][r] = 0.f;
    float m_run = -INFINITY, l_run = 0.f;

    for (int k0 = 0; k0 < Ss; k0 += KBLK) {
        {
            const float* p0 = kbase + (size_t)(k0 + krs) * Dd + kc8;
            const float4 a = *reinterpret_cast<const float4*>(p0);
            const float4 c = *reinterpret_cast<const float4*>(p0 + 4);
            float xs[8] = {a.x, a.y, a.z, a.w, c.x, c.y, c.z, c.w};
            bf16x8 h8, l8;
#pragma unroll
            for (int i = 0; i < 8; ++i) {
                __bf16 h = (__bf16)xs[i];
                h8[i] = h;
                l8[i] = (__bf16)(xs[i] - (float)h);
            }
            *reinterpret_cast<bf16x8*>(&sKhi[kidx]) = h8;
            *reinterpret_cast<bf16x8*>(&sKlo[kidx]) = l8;
        }
        {
            bf16x8 v8;
#pragma unroll
            for (int j = 0; j < 8; ++j) v8[j] = (__bf16)vbase[(size_t)(k0 + vk8 + j) * Dd + vd];
            *reinterpret_cast<bf16x8*>(&sVt[vidx]) = v8;
        }
        __syncthreads();

        float z[2][4];
#pragma unroll
        for (int t = 0; t < 2; ++t) {
            const int krow = t * 16 + q15;
            f32x4 acc;
            acc[0] = acc[1] = acc[2] = acc[3] = 0.f;
#pragma unroll
            for (int ds = 0; ds < 2; ++ds) {
                const int ci = (ds * 32 + g * 8) ^ ((krow & 7) << 3);
                const bf16x8 kh = *reinterpret_cast<const bf16x8*>(&sKhi[krow * Dd + ci]);
                const bf16x8 kl = *reinterpret_cast<const bf16x8*>(&sKlo[krow * Dd + ci]);
                acc = __builtin_amdgcn_mfma_f32_16x16x32_bf16(kh, qhi[ds], acc, 0, 0, 0);
                acc = __builtin_amdgcn_mfma_f32_16x16x32_bf16(kl, qhi[ds], acc, 0, 0, 0);
                acc = __builtin_amdgcn_mfma_f32_16x16x32_bf16(kh, qlo[ds], acc, 0, 0, 0);
            }
#pragma unroll
            for (int r = 0; r < 4; ++r) z[t][r] = acc[r] * scale;
        }

        float tmax = z[0][0];
#pragma unroll
        for (int t = 0; t < 2; ++t)
#pragma unroll
            for (int r = 0; r < 4; ++r) tmax = fmaxf(tmax, z[t][r]);
        tmax = fmaxf(tmax, __shfl_xor(tmax, 16));
        tmax = fmaxf(tmax, __shfl_xor(tmax, 32));
        const float m_new = fmaxf(m_run, tmax);

        float pz[2][4];
        float tsum = 0.f;
#pragma unroll
        for (int t = 0; t < 2; ++t)
#pragma unroll
            for (int r = 0; r < 4; ++r) {
                const float e = __builtin_amdgcn_exp2f((z[t][r] - m_new) * kLOG2E);
                pz[t][r] = e;
                tsum += e;
            }
        tsum += __shfl_xor(tsum, 16);
        tsum += __shfl_xor(tsum, 32);
        const float fac = __builtin_amdgcn_exp2f((m_run - m_new) * kLOG2E);
        l_run = l_run * fac + tsum;
        m_run = m_new;

#pragma unroll
        for (int t = 0; t < 2; ++t) {
            bf16x4 pb;
#pragma unroll
            for (int r = 0; r < 4; ++r) pb[r] = (__bf16)pz[t][r];
            const int pidx = q15 * KBLK + ((t * 16 + g * 4) ^ ((q15 & 3) << 3));
            *reinterpret_cast<bf16x4*>(&sP[w][pidx]) = pb;
        }
        {
            const float fr0 = __shfl(fac, g * 4 + 0);
            const float fr1 = __shfl(fac, g * 4 + 1);
            const float fr2 = __shfl(fac, g * 4 + 2);
            const float fr3 = __shfl(fac, g * 4 + 3);
#pragma unroll
            for (int dt = 0; dt < 4; ++dt) {
                Oacc[dt][0] *= fr0; Oacc[dt][1] *= fr1;
                Oacc[dt][2] *= fr2; Oacc[dt][3] *= fr3;
            }
        }
        const int paidx = q15 * KBLK + ((g * 8) ^ ((q15 & 3) << 3));
        const bf16x8 pa = *reinterpret_cast<const bf16x8*>(&sP[w][paidx]);
#pragma unroll
        for (int dt = 0; dt < 4; ++dt) {
            const int dd = dt * 16 + q15;
            const bf16x8 vf =
                *reinterpret_cast<const bf16x8*>(&sVt[dd * KBLK + ((g * 8) ^ ((dd & 3) << 3))]);
            Oacc[dt] = __builtin_amdgcn_mfma_f32_16x16x32_bf16(pa, vf, Oacc[dt], 0, 0, 0);
        }
        __syncthreads();
    }

    const float invl = 1.0f / l_run;
    float il[4];
#pragma unroll
    for (int r = 0; r < 4; ++r) il[r] = __shfl(invl, g * 4 + r);
    float* obase = Out + (((size_t)b * Ss) + q0 + w * 16) * Dd;
#pragma unroll
    for (int dt = 0; dt < 4; ++dt)
#pragma unroll
        for (int r = 0; r < 4; ++r)
            obase[(size_t)(g * 4 + r) * Dd + dt * 16 + q15] = Oacc[dt][r] * il[r];
}

extern "C" void kernel_launch(void* const* d_in, const int* in_sizes, int n_in,
                              void* d_out, int out_size, void* d_ws, size_t ws_size,
                              hipStream_t stream)
{
    const float* q = (const float*)d_in[0];
    const float* k = (const float*)d_in[1];
    const float* v = (const float*)d_in[2];
    const float* inv_scale = (const float*)d_in[3];
    float* out = (float*)d_out;
    (void)in_sizes; (void)n_in; (void)out_size;

    const size_t NKV = (size_t)Bb * Ss * Dd;                 // elements per K/V tensor
    const size_t need = NKV * 3 * sizeof(_Float16);          // Khi + Klo + Vt

    if (ws_size >= need) {
        _Float16* Khi = (_Float16*)d_ws;
        _Float16* Klo = Khi + NKV;
        _Float16* Vt = Klo + NKV;
        hipLaunchKernelGGL(prep_f16s, dim3(KP_BLOCKS + VT_BLOCKS), dim3(256), 0, stream,
                           k, v, Khi, Klo, Vt);
        hipLaunchKernelGGL(attn_fwd_v10, dim3(Bb * (Ss / QBLK)), dim3(256), 0, stream,
                           q, inv_scale, Khi, Klo, Vt, out);
    } else {
        hipLaunchKernelGGL(attn_fwd_fallback, dim3(Bb * 64), dim3(256), 0, stream,
                           q, k, v, inv_scale, out);
    }
}